// Round 1
// baseline (476.182 us; speedup 1.0000x reference)
//
#include <hip/hip_runtime.h>
#include <hip/hip_bf16.h>
#include <stdint.h>

// Q2Linear: out[m,n] = sum_kb scales[n,kb] * sum_i x[m,kb*128+i] * w[n,kb*128+i]
// M=1024 (tokens), N=4096, K=4096, scale block = 128.
// Strategy: bf16 MFMA GEMM (threshold 0.62 allows bf16), scale folded into
// staged weight. 128x128 tile, BK=64, 256 threads (4 waves, 64x64 each).

#define BM 128
#define BN 128
#define BK 64
#define LDK 72   // BK + 8 element pad -> 144 B row stride (16B-aligned, 2-way max bank conflict)

typedef __attribute__((ext_vector_type(8))) short short8;
typedef __attribute__((ext_vector_type(4))) float floatx4;
typedef __attribute__((ext_vector_type(4))) unsigned short ushortx4;
typedef __attribute__((ext_vector_type(4))) int intx4;

__device__ __forceinline__ unsigned short f2bf(float f) {
    union { float f; unsigned u; } v; v.f = f;
    unsigned u = v.u;
    return (unsigned short)((u + 0x7FFFu + ((u >> 16) & 1u)) >> 16);  // RNE
}

__global__ __launch_bounds__(256) void q2_gemm(
    const float* __restrict__ x,      // [M][K] fp32
    const int* __restrict__ wq,       // [N][K] int32 (values -2..1)
    const float* __restrict__ scales, // [N][K/128] fp32
    float* __restrict__ out,          // [M][N] fp32
    int M, int N, int K)
{
    __shared__ unsigned short As[BM * LDK];  // bf16 bits, [m][k]
    __shared__ unsigned short Bs[BN * LDK];  // bf16 bits of w*scale, [n][k]

    const int tid  = threadIdx.x;
    const int lane = tid & 63;
    const int wave = tid >> 6;
    const int wm   = (wave & 1) * 64;   // wave's m offset in tile
    const int wn   = (wave >> 1) * 64;  // wave's n offset in tile
    const int r16  = lane & 15;
    const int quad = lane >> 4;

    const int mTiles = M / BM;                 // 8
    const int mT = blockIdx.x % mTiles;        // same m-tile -> same XCD (L2 reuse of x)
    const int nT = blockIdx.x / mTiles;
    const int mBase = mT * BM;
    const int nBase = nT * BN;
    const int NBLK  = K >> 7;                  // scale blocks of 128

    floatx4 acc[4][4];
#pragma unroll
    for (int i = 0; i < 4; ++i)
#pragma unroll
        for (int j = 0; j < 4; ++j)
            acc[i][j] = (floatx4){0.f, 0.f, 0.f, 0.f};

    for (int it = 0; it < K / BK; ++it) {
        const int k0 = it * BK;
        const int kb = k0 >> 7;  // uniform for whole BK=64 slab

        // ---- stage A: 128x64 fp32 -> bf16.  2048 float4 chunks / 256 thr = 8 each
#pragma unroll
        for (int c = 0; c < 8; ++c) {
            int lin4 = c * 256 + tid;
            int row  = lin4 >> 4;            // 16 float4-chunks per row
            int col  = (lin4 & 15) << 2;
            floatx4 xv = *(const floatx4*)(x + (row + mBase) * K + k0 + col);
            ushortx4 h;
            h[0] = f2bf(xv[0]); h[1] = f2bf(xv[1]);
            h[2] = f2bf(xv[2]); h[3] = f2bf(xv[3]);
            *(ushortx4*)(&As[row * LDK + col]) = h;
        }

        // ---- stage B: 128x64 int32 -> bf16(w * scale). 2048 intx4 chunks / 256 thr = 8 each
#pragma unroll
        for (int c = 0; c < 8; ++c) {
            int lin4 = c * 256 + tid;
            int row  = lin4 >> 4;
            int col  = (lin4 & 15) << 2;
            intx4 wv = *(const intx4*)(wq + (size_t)(row + nBase) * K + k0 + col);
            float s  = scales[(row + nBase) * NBLK + kb];
            ushortx4 h;
            h[0] = f2bf((float)wv[0] * s);
            h[1] = f2bf((float)wv[1] * s);
            h[2] = f2bf((float)wv[2] * s);
            h[3] = f2bf((float)wv[3] * s);
            *(ushortx4*)(&Bs[row * LDK + col]) = h;
        }

        __syncthreads();

        // ---- MFMA over the BK slab (two K=32 steps)
#pragma unroll
        for (int kk = 0; kk < BK; kk += 32) {
            short8 av[4], bv[4];
#pragma unroll
            for (int i = 0; i < 4; ++i)
                av[i] = *(const short8*)(&As[(wm + i * 16 + r16) * LDK + kk + quad * 8]);
#pragma unroll
            for (int j = 0; j < 4; ++j)
                bv[j] = *(const short8*)(&Bs[(wn + j * 16 + r16) * LDK + kk + quad * 8]);
#pragma unroll
            for (int i = 0; i < 4; ++i)
#pragma unroll
                for (int j = 0; j < 4; ++j)
                    acc[i][j] = __builtin_amdgcn_mfma_f32_16x16x32_bf16(
                        av[i], bv[j], acc[i][j], 0, 0, 0);
        }

        __syncthreads();
    }

    // ---- epilogue: C/D layout col = lane&15 (n), row = quad*4 + reg (m)
#pragma unroll
    for (int i = 0; i < 4; ++i) {
#pragma unroll
        for (int r = 0; r < 4; ++r) {
            int mg = mBase + wm + i * 16 + quad * 4 + r;
            float* orow = out + (size_t)mg * N + nBase + wn + r16;
#pragma unroll
            for (int j = 0; j < 4; ++j)
                orow[j * 16] = acc[i][j][r];
        }
    }
}

extern "C" void kernel_launch(void* const* d_in, const int* in_sizes, int n_in,
                              void* d_out, int out_size, void* d_ws, size_t ws_size,
                              hipStream_t stream) {
    const float* x      = (const float*)d_in[0];
    const int*   wq     = (const int*)d_in[1];    // harness uploads integer inputs as int32
    const float* scales = (const float*)d_in[2];
    float*       out    = (float*)d_out;

    const int K = 4096;
    const int N = 4096;
    const int M = in_sizes[0] / K;  // 1024

    dim3 grid((M / BM) * (N / BN));  // 8 * 32 = 256 blocks
    q2_gemm<<<grid, 256, 0, stream>>>(x, wq, scales, out, M, N, K);
}

// Round 2
// 183.673 us; speedup vs baseline: 2.5926x; 2.5926x over previous
//
#include <hip/hip_runtime.h>
#include <stdint.h>

// Q2Linear: out = x @ (w*scale)^T.  M=1024, N=4096, K=4096, scale block=128.
// Pass 1: convert x (fp32) and w (int32 {-2..1} x per-block scale) to bf16 in d_ws.
// Pass 2: bf16 MFMA GEMM, 128x128x64 tiles, global_load_lds(16B) staging,
//         double-buffered LDS, XOR-swizzled layout (conflict-free ds_read_b128).

#define BM 128
#define BN 128
#define BK 64

typedef __attribute__((ext_vector_type(8))) short short8;
typedef __attribute__((ext_vector_type(4))) float floatx4;
typedef __attribute__((ext_vector_type(4))) unsigned short ushortx4;
typedef __attribute__((ext_vector_type(4))) int intx4;

typedef const __attribute__((address_space(1))) void global_cvoid;
typedef __attribute__((address_space(3))) void lds_void;

__device__ __forceinline__ unsigned short f2bf(float f) {
    union { float f; unsigned u; } v; v.f = f;
    return (unsigned short)((v.u + 0x7FFFu + ((v.u >> 16) & 1u)) >> 16);  // RNE
}

// ---- pass 1a: x fp32 -> bf16 -------------------------------------------------
__global__ __launch_bounds__(256) void conv_x(const float* __restrict__ x,
                                              unsigned short* __restrict__ xb, int n4) {
    int t = blockIdx.x * 256 + threadIdx.x;
    if (t < n4) {
        floatx4 v = ((const floatx4*)x)[t];
        ushortx4 h;
        h[0] = f2bf(v[0]); h[1] = f2bf(v[1]); h[2] = f2bf(v[2]); h[3] = f2bf(v[3]);
        ((ushortx4*)xb)[t] = h;
    }
}

// ---- pass 1b: w int32 * scale -> bf16 (scale folded, once) -------------------
__global__ __launch_bounds__(256) void conv_w(const int* __restrict__ wq,
                                              const float* __restrict__ scales,
                                              unsigned short* __restrict__ wb) {
    const int K = 4096;
    int t = blockIdx.x * 256 + threadIdx.x;   // one 4-element chunk per thread
    int k4 = t & (K / 4 - 1);                 // chunk index within row
    int n  = t >> 10;                         // K/4 = 1024 chunks per row
    float s = scales[n * (K >> 7) + (k4 >> 5)];  // 128-elem scale blocks
    intx4 w = ((const intx4*)wq)[t];
    ushortx4 h;
    h[0] = f2bf((float)w[0] * s); h[1] = f2bf((float)w[1] * s);
    h[2] = f2bf((float)w[2] * s); h[3] = f2bf((float)w[3] * s);
    ((ushortx4*)wb)[t] = h;
}

// ---- pass 2: bf16 GEMM -------------------------------------------------------
// LDS layout per 128x64 tile: row r (128B) holds 8 chunks of 16B; global chunk c
// stored at position c ^ (r&7).  Fragment ds_read_b128 then spreads the wave's
// 64 lanes evenly over all 32 banks (8/bank = minimum phases, conflict-free).
// global_load_lds writes base+lane*16, so lane fetches global chunk
// (lane&7) ^ ((lane>>3)&7) of row base+(lane>>3) -> swizzle by address permute.

__global__ __launch_bounds__(256) void q2_gemm(const unsigned short* __restrict__ xb,
                                               const unsigned short* __restrict__ wb,
                                               float* __restrict__ out,
                                               int M, int N, int K) {
    __shared__ unsigned short As[2][BM * BK];  // 16 KB each
    __shared__ unsigned short Bs[2][BN * BK];

    const int tid  = threadIdx.x;
    const int lane = tid & 63;
    const int wave = tid >> 6;
    const int wm   = (wave & 1) * 64;
    const int wn   = (wave >> 1) * 64;
    const int r16  = lane & 15;
    const int quad = lane >> 4;
    const int sw   = r16 & 7;

    // block swizzle: XCD = bid%8 (round-robin heuristic); give each XCD 4 n-tiles
    // (4x1MB wb slabs ~ L2-resident) and stream xb (8MB, L3-resident).
    const int bid = blockIdx.x;
    const int nT  = (bid & 7) + ((bid >> 6) << 3);
    const int mT  = (bid >> 3) & 7;
    const int mBase = mT * BM, nBase = nT * BN;

    // staging: per wave 4 instrs for A + 4 for B, each covers 8 rows x 64 cols
    const int rg = lane >> 3;                // row within 8-row group
    const int cs = (lane & 7) ^ rg;          // swizzled global chunk
    const unsigned short* gA = xb + (size_t)(mBase + wave * 32 + rg) * K + cs * 8;
    const unsigned short* gB = wb + (size_t)(nBase + wave * 32 + rg) * K + cs * 8;
    const int ldsRow = wave * 32;            // wave's first row in tile

    floatx4 acc[4][4];
#pragma unroll
    for (int i = 0; i < 4; ++i)
#pragma unroll
        for (int j = 0; j < 4; ++j) acc[i][j] = (floatx4){0.f, 0.f, 0.f, 0.f};

#define STAGE(BUF, K0)                                                          \
    {                                                                           \
        _Pragma("unroll")                                                       \
        for (int t = 0; t < 4; ++t) {                                           \
            __builtin_amdgcn_global_load_lds(                                   \
                (global_cvoid*)(gA + (size_t)(t * 8) * K + (K0)),               \
                (lds_void*)&As[BUF][(ldsRow + t * 8) * BK], 16, 0, 0);          \
            __builtin_amdgcn_global_load_lds(                                   \
                (global_cvoid*)(gB + (size_t)(t * 8) * K + (K0)),               \
                (lds_void*)&Bs[BUF][(ldsRow + t * 8) * BK], 16, 0, 0);          \
        }                                                                       \
    }

#define COMPUTE(BUF)                                                            \
    {                                                                           \
        _Pragma("unroll")                                                       \
        for (int kp = 0; kp < 2; ++kp) {                                        \
            short8 av[4], bv[4];                                                \
            _Pragma("unroll")                                                   \
            for (int i = 0; i < 4; ++i)                                         \
                av[i] = *(const short8*)&As[BUF][(wm + i * 16 + r16) * BK +     \
                                                 (((quad + 4 * kp) ^ sw) << 3)];\
            _Pragma("unroll")                                                   \
            for (int j = 0; j < 4; ++j)                                         \
                bv[j] = *(const short8*)&Bs[BUF][(wn + j * 16 + r16) * BK +     \
                                                 (((quad + 4 * kp) ^ sw) << 3)];\
            _Pragma("unroll")                                                   \
            for (int i = 0; i < 4; ++i)                                         \
                _Pragma("unroll")                                               \
                for (int j = 0; j < 4; ++j)                                     \
                    acc[i][j] = __builtin_amdgcn_mfma_f32_16x16x32_bf16(        \
                        av[i], bv[j], acc[i][j], 0, 0, 0);                      \
        }                                                                       \
    }

    const int NIT = K / BK;  // 64
    STAGE(0, 0)
    __syncthreads();
    for (int it = 0; it < NIT; it += 2) {
        if (it + 1 < NIT) STAGE(1, (it + 1) * BK)   // prefetch -> overlap compute
        COMPUTE(0)
        __syncthreads();
        if (it + 2 < NIT) STAGE(0, (it + 2) * BK)
        COMPUTE(1)
        __syncthreads();
    }

    // epilogue: C/D layout col=lane&15 (n), row=quad*4+reg (m)
#pragma unroll
    for (int i = 0; i < 4; ++i) {
#pragma unroll
        for (int r = 0; r < 4; ++r) {
            int mg = mBase + wm + i * 16 + quad * 4 + r;
            float* orow = out + (size_t)mg * N + nBase + wn + r16;
#pragma unroll
            for (int j = 0; j < 4; ++j) orow[j * 16] = acc[i][j][r];
        }
    }
#undef STAGE
#undef COMPUTE
}

extern "C" void kernel_launch(void* const* d_in, const int* in_sizes, int n_in,
                              void* d_out, int out_size, void* d_ws, size_t ws_size,
                              hipStream_t stream) {
    const float* x      = (const float*)d_in[0];
    const int*   wq     = (const int*)d_in[1];
    const float* scales = (const float*)d_in[2];
    float*       out    = (float*)d_out;

    const int K = 4096, N = 4096;
    const int M = in_sizes[0] / K;  // 1024

    unsigned short* xb = (unsigned short*)d_ws;                          // M*K*2 = 8 MB
    unsigned short* wb = (unsigned short*)((char*)d_ws + (size_t)M * K * 2);  // N*K*2 = 32 MB

    conv_x<<<(M * K / 4 + 255) / 256, 256, 0, stream>>>(x, xb, M * K / 4);
    conv_w<<<(N * K / 4) / 256, 256, 0, stream>>>(wq, scales, wb);
    q2_gemm<<<(M / BM) * (N / BN), 256, 0, stream>>>(xb, wb, out, M, N, K);
}